// Round 24
// baseline (59.921 us; speedup 1.0000x reference)
//
#include <hip/hip_runtime.h>

typedef __attribute__((ext_vector_type(4))) float f32x4;
typedef __attribute__((ext_vector_type(2))) unsigned u32x2;
typedef __attribute__((ext_vector_type(8))) short bf16x8;

constexpr int Bsz = 4096, Asz = 32, Isz = 256, Osz = 256;
constexpr int NI = 16;                 // iterations of 32-row super-tiles

// packed f32x2 -> bf16x2 (RNE); no builtin on gfx950
__device__ inline unsigned cvtpk(float lo, float hi) {
    unsigned r;
    asm("v_cvt_pk_bf16_f32 %0, %1, %2" : "=v"(r) : "v"(lo), "v"(hi));
    return r;
}

// ---------------------------------------------------------------------------
// r24 = r23 (proven 57.0us PASS) + ONE change: the 16-store burst of
// iteration tn is DEFERRED one phase — acc is held in registers across the
// barrier and stored at the TOP of iteration tn+1. The write drain then
// overlaps the whole next compute phase instead of colliding with the
// barrier (r23 accounting: phases were ADDING — LDS 3.0K + HBM ~5K cyc/iter).
// Everything else identical: 256 blocks (1/CU), 512 threads = 8 waves,
// LDS 160 KB exact (sA 2x16KB dbuf bf16 + sB 128KB packed B), 32-row
// iterations, reg-staged bf16 A fill (pinned loads, compiler-tracked),
// lgkmcnt(0) + raw s_barrier per iteration, NO vmcnt anywhere.
// ---------------------------------------------------------------------------
__global__ __launch_bounds__(512, 2) void al_gemm(const float* __restrict__ x,
                                                  const float* __restrict__ wsrc,
                                                  const float* __restrict__ bias,
                                                  float* __restrict__ out)
{
    __shared__ char sA[2][16384];   // 32 rows x 512B (bf16), chunk-XOR swizzled
    __shared__ char sB[131072];     // packed B, fragment-linear

    // 256 blocks: xcd p&7 hosts a in {4k..4k+3}; rowgroup p>>5 -> 512 rows.
    const int p  = blockIdx.x;
    const int a  = (p & 7) * 4 + ((p >> 3) & 3);
    const int b0 = (p >> 5) * 512;

    const int t    = threadIdx.x;
    const int w    = t >> 6;          // wave 0..7
    const int lane = t & 63;
    const int llo  = lane & 15, lhi = lane >> 4;

    // ---- A fill (reg-staged): wave w covers super-tile-local rows 4w..4w+3.
    // Lane holds f32 k = lane*4..+3 of its row -> 2 cvt_pk -> ds_write_b64 at
    // swizzled chunk ((lane>>1)^row)*16 + (lane&1)*8.
    const float* fs[4];
    int wadr[4];
#pragma unroll
    for (int j = 0; j < 4; ++j) {
        const int lr = 4 * w + j;
        fs[j]   = x + ((size_t)(b0 + lr) * Asz + a) * Isz + lane * 4;
        wadr[j] = lr * 512 + (((lane >> 1) ^ lr) << 4) + (lane & 1) * 8;
    }

    f32x4 L[4];                       // in-flight fill registers (16 VGPR)
#pragma unroll
    for (int j = 0; j < 4; ++j) L[j] = *(const f32x4*)fs[j];
    asm volatile("" : "+v"(L[0]), "+v"(L[1]), "+v"(L[2]), "+v"(L[3]));

    // ---- pack w[a] f32 -> sB bf16, fragment-linear — COALESCED (r19):
    // slot s = i*512+t -> 8 contiguous f32 at wa+s*8 = lane-slot of frag:
    // o = s>>5, kt = (s>>2)&7, nf = s>>9, lane_ = (o&15) | ((s&3)<<4).
    {
        const float* wa = wsrc + (size_t)a * (Osz * Isz);
#pragma unroll
        for (int i = 0; i < 16; ++i) {
            const int s     = i * 512 + t;
            const int o     = s >> 5;
            const int kt    = (s >> 2) & 7;
            const int nf    = s >> 9;
            const int lane_ = (o & 15) | ((s & 3) << 4);
            f32x4 lo = *(const f32x4*)(wa + (size_t)s * 8);
            f32x4 hi = *(const f32x4*)(wa + (size_t)s * 8 + 4);
            union { bf16x8 v; unsigned u[4]; } r;
            r.u[0] = cvtpk(lo[0], lo[1]); r.u[1] = cvtpk(lo[2], lo[3]);
            r.u[2] = cvtpk(hi[0], hi[1]); r.u[3] = cvtpk(hi[2], hi[3]);
            *(bf16x8*)&sB[(((kt * 16 + nf) * 64) + lane_) * 16] = r.v;
        }
    }

    const float bv0 = bias[a * Osz + w * 32 + llo];
    const float bv1 = bias[a * Osz + w * 32 + 16 + llo];

    // write L(0) into sA[0]
#pragma unroll
    for (int j = 0; j < 4; ++j)
        *(u32x2*)&sA[0][wadr[j]] = (u32x2){cvtpk(L[j][0], L[j][1]), cvtpk(L[j][2], L[j][3])};

    __syncthreads();   // one-time full drain: sA[0] + sB visible

    // compute-side A addrs: tile0 row = llo, tile1 row = llo+16;
    // chunk c = kt*4+lhi read at (c ^ row)*16.
    const int lr1 = llo + 16;

    // deferred-store state (held across the barrier)
    f32x4 pAcc00, pAcc01, pAcc10, pAcc11;
    float *pOp0 = nullptr, *pOp1 = nullptr;

    for (int tn = 0; tn < NI; ++tn) {
        if (tn < NI - 1) {             // issue fill(tn+1); hides under compute
            const size_t o_ = (size_t)(tn + 1) * (32 * Asz * Isz);
#pragma unroll
            for (int j = 0; j < 4; ++j) L[j] = *(const f32x4*)(fs[j] + o_);
            asm volatile("" : "+v"(L[0]), "+v"(L[1]), "+v"(L[2]), "+v"(L[3]));
        }

        // deferred stores of iteration tn-1: issued at phase TOP so the write
        // drain overlaps this whole compute phase (never waited on).
        if (tn > 0) {
#pragma unroll
            for (int r2 = 0; r2 < 4; ++r2) {
                pOp0[(size_t)r2 * Asz * Osz]      = pAcc00[r2];
                pOp0[(size_t)r2 * Asz * Osz + 16] = pAcc01[r2];
                pOp1[(size_t)r2 * Asz * Osz]      = pAcc10[r2];
                pOp1[(size_t)r2 * Asz * Osz + 16] = pAcc11[r2];
            }
        }

        const char* As = &sA[tn & 1][0];
        f32x4 acc00 = (f32x4)(bv0), acc01 = (f32x4)(bv1);   // tile0
        f32x4 acc10 = (f32x4)(bv0), acc11 = (f32x4)(bv1);   // tile1
        __builtin_amdgcn_s_setprio(1);
#pragma unroll
        for (int kt = 0; kt < 8; ++kt) {
            const int c = kt * 4 + lhi;
            const bf16x8 aF0 = *(const bf16x8*)&As[llo * 512 + ((c ^ llo) << 4)];
            const bf16x8 aF1 = *(const bf16x8*)&As[lr1 * 512 + ((c ^ lr1) << 4)];
            const bf16x8 bF0 = *(const bf16x8*)&sB[(kt * 16 + 2 * w) * 1024 + lane * 16];
            const bf16x8 bF1 = *(const bf16x8*)&sB[(kt * 16 + 2 * w + 1) * 1024 + lane * 16];
            acc00 = __builtin_amdgcn_mfma_f32_16x16x32_bf16(aF0, bF0, acc00, 0, 0, 0);
            acc01 = __builtin_amdgcn_mfma_f32_16x16x32_bf16(aF0, bF1, acc01, 0, 0, 0);
            acc10 = __builtin_amdgcn_mfma_f32_16x16x32_bf16(aF1, bF0, acc10, 0, 0, 0);
            acc11 = __builtin_amdgcn_mfma_f32_16x16x32_bf16(aF1, bF1, acc11, 0, 0, 0);
        }
        __builtin_amdgcn_s_setprio(0);

        // save acc + pointers for the deferred store at tn+1's top
        pAcc00 = acc00; pAcc01 = acc01; pAcc10 = acc10; pAcc11 = acc11;
        const int trow = b0 + tn * 32 + lhi * 4;
        pOp0 = out + ((size_t)trow * Asz + a) * Osz + w * 32 + llo;
        pOp1 = pOp0 + (size_t)16 * Asz * Osz;

        if (tn < NI - 1) {             // cvt + write fill into the other buffer
            char* Ad = &sA[(tn + 1) & 1][0];
#pragma unroll
            for (int j = 0; j < 4; ++j)
                *(u32x2*)&Ad[wadr[j]] = (u32x2){cvtpk(L[j][0], L[j][1]), cvtpk(L[j][2], L[j][3])};
        }

        // ds_writes visible to all; stores/loads NOT drained (raw barrier).
        asm volatile("s_waitcnt lgkmcnt(0)" ::: "memory");
        __builtin_amdgcn_s_barrier();
    }

    // epilogue: final deferred store (tn = NI-1)
#pragma unroll
    for (int r2 = 0; r2 < 4; ++r2) {
        pOp0[(size_t)r2 * Asz * Osz]      = pAcc00[r2];
        pOp0[(size_t)r2 * Asz * Osz + 16] = pAcc01[r2];
        pOp1[(size_t)r2 * Asz * Osz]      = pAcc10[r2];
        pOp1[(size_t)r2 * Asz * Osz + 16] = pAcc11[r2];
    }
}

extern "C" void kernel_launch(void* const* d_in, const int* in_sizes, int n_in,
                              void* d_out, int out_size, void* d_ws, size_t ws_size,
                              hipStream_t stream) {
    const float* x    = (const float*)d_in[0];
    const float* w    = (const float*)d_in[1];
    const float* bias = (const float*)d_in[2];
    float* out        = (float*)d_out;
    al_gemm<<<dim3(256), dim3(512), 0, stream>>>(x, w, bias, out);
}

// Round 25
// 55.266 us; speedup vs baseline: 1.0842x; 1.0842x over previous
//
#include <hip/hip_runtime.h>

typedef __attribute__((ext_vector_type(4))) float f32x4;
typedef __attribute__((ext_vector_type(2))) unsigned u32x2;
typedef __attribute__((ext_vector_type(8))) short bf16x8;

constexpr int Bsz = 4096, Asz = 32, Isz = 256, Osz = 256;
constexpr int NI = 16;                 // iterations of 32-row super-tiles

// packed f32x2 -> bf16x2 (RNE); no builtin on gfx950
__device__ inline unsigned cvtpk(float lo, float hi) {
    unsigned r;
    asm("v_cvt_pk_bf16_f32 %0, %1, %2" : "=v"(r) : "v"(lo), "v"(hi));
    return r;
}

// ---------------------------------------------------------------------------
// r25 = r23 (proven 57.0us PASS) + 2-DEEP fill pipeline: two static register
// sets LA/LB (loop unrolled x2, rule #20); loads for F(tn+2) issue at the top
// of compute(tn) -> ~2 phases (~1.5K cyc) of latency cover instead of <1
// (r23's exposed-latency gap: 8.5K cyc/iter measured vs 6.4K HBM pace).
// Everything else identical: 256 blocks (1/CU), 512 threads = 8 waves,
// LDS 160 KB exact (sA 2x16KB dbuf bf16 + sB 128KB packed B), 32-row
// iterations, lgkmcnt(0) + raw s_barrier per iteration, NO vmcnt anywhere,
// stores at compute end (r24's deferral regressed — reverted).
// ---------------------------------------------------------------------------
__global__ __launch_bounds__(512, 2) void al_gemm(const float* __restrict__ x,
                                                  const float* __restrict__ wsrc,
                                                  const float* __restrict__ bias,
                                                  float* __restrict__ out)
{
    __shared__ char sA[2][16384];   // 32 rows x 512B (bf16), chunk-XOR swizzled
    __shared__ char sB[131072];     // packed B, fragment-linear

    // 256 blocks: xcd p&7 hosts a in {4k..4k+3}; rowgroup p>>5 -> 512 rows.
    const int p  = blockIdx.x;
    const int a  = (p & 7) * 4 + ((p >> 3) & 3);
    const int b0 = (p >> 5) * 512;

    const int t    = threadIdx.x;
    const int w    = t >> 6;          // wave 0..7
    const int lane = t & 63;
    const int llo  = lane & 15, lhi = lane >> 4;

    // ---- A fill (reg-staged): wave w covers super-tile-local rows 4w..4w+3.
    // Lane holds f32 k = lane*4..+3 of its row -> 2 cvt_pk -> ds_write_b64 at
    // swizzled chunk ((lane>>1)^row)*16 + (lane&1)*8.
    const float* fs[4];
    int wadr[4];
#pragma unroll
    for (int j = 0; j < 4; ++j) {
        const int lr = 4 * w + j;
        fs[j]   = x + ((size_t)(b0 + lr) * Asz + a) * Isz + lane * 4;
        wadr[j] = lr * 512 + (((lane >> 1) ^ lr) << 4) + (lane & 1) * 8;
    }
    const size_t STEP = (size_t)32 * Asz * Isz;   // 32 rows of x

    f32x4 LA[4], LB[4];               // 2-deep fill pipeline (32 VGPR)

#define FISSUE(Lset, tn) {                                                     \
    const size_t o_ = (size_t)(tn) * STEP;                                     \
    _Pragma("unroll")                                                          \
    for (int j = 0; j < 4; ++j) Lset[j] = *(const f32x4*)(fs[j] + o_);         \
    asm volatile("" : "+v"(Lset[0]), "+v"(Lset[1]), "+v"(Lset[2]), "+v"(Lset[3])); }

#define FWRITE(Lset, buf) {                                                    \
    char* Ad = &sA[buf][0];                                                    \
    _Pragma("unroll")                                                          \
    for (int j = 0; j < 4; ++j)                                                \
        *(u32x2*)&Ad[wadr[j]] =                                                \
            (u32x2){cvtpk(Lset[j][0], Lset[j][1]), cvtpk(Lset[j][2], Lset[j][3])}; }

    FISSUE(LA, 0);                    // F(0) in flight during the pack

    // ---- pack w[a] f32 -> sB bf16, fragment-linear — COALESCED (r19):
    // slot s = i*512+t -> 8 contiguous f32 at wa+s*8 = lane-slot of frag:
    // o = s>>5, kt = (s>>2)&7, nf = s>>9, lane_ = (o&15) | ((s&3)<<4).
    {
        const float* wa = wsrc + (size_t)a * (Osz * Isz);
#pragma unroll
        for (int i = 0; i < 16; ++i) {
            const int s     = i * 512 + t;
            const int o     = s >> 5;
            const int kt    = (s >> 2) & 7;
            const int nf    = s >> 9;
            const int lane_ = (o & 15) | ((s & 3) << 4);
            f32x4 lo = *(const f32x4*)(wa + (size_t)s * 8);
            f32x4 hi = *(const f32x4*)(wa + (size_t)s * 8 + 4);
            union { bf16x8 v; unsigned u[4]; } r;
            r.u[0] = cvtpk(lo[0], lo[1]); r.u[1] = cvtpk(lo[2], lo[3]);
            r.u[2] = cvtpk(hi[0], hi[1]); r.u[3] = cvtpk(hi[2], hi[3]);
            *(bf16x8*)&sB[(((kt * 16 + nf) * 64) + lane_) * 16] = r.v;
        }
    }

    const float bv0 = bias[a * Osz + w * 32 + llo];
    const float bv1 = bias[a * Osz + w * 32 + 16 + llo];

    FWRITE(LA, 0);                    // sA[0] = F(0)
    FISSUE(LB, 1);                    // F(1) in flight across the sync

    __syncthreads();   // one-time full drain: sA[0] + sB visible

    // compute-side A addrs: tile0 row = llo, tile1 row = llo+16;
    // chunk c = kt*4+lhi read at (c ^ row)*16.
    const int lr1 = llo + 16;

    auto COMPUTE_STORE = [&](const char* As, int tn) {
        f32x4 acc00 = (f32x4)(bv0), acc01 = (f32x4)(bv1);   // tile0
        f32x4 acc10 = (f32x4)(bv0), acc11 = (f32x4)(bv1);   // tile1
        __builtin_amdgcn_s_setprio(1);
#pragma unroll
        for (int kt = 0; kt < 8; ++kt) {
            const int c = kt * 4 + lhi;
            const bf16x8 aF0 = *(const bf16x8*)&As[llo * 512 + ((c ^ llo) << 4)];
            const bf16x8 aF1 = *(const bf16x8*)&As[lr1 * 512 + ((c ^ lr1) << 4)];
            const bf16x8 bF0 = *(const bf16x8*)&sB[(kt * 16 + 2 * w) * 1024 + lane * 16];
            const bf16x8 bF1 = *(const bf16x8*)&sB[(kt * 16 + 2 * w + 1) * 1024 + lane * 16];
            acc00 = __builtin_amdgcn_mfma_f32_16x16x32_bf16(aF0, bF0, acc00, 0, 0, 0);
            acc01 = __builtin_amdgcn_mfma_f32_16x16x32_bf16(aF0, bF1, acc01, 0, 0, 0);
            acc10 = __builtin_amdgcn_mfma_f32_16x16x32_bf16(aF1, bF0, acc10, 0, 0, 0);
            acc11 = __builtin_amdgcn_mfma_f32_16x16x32_bf16(aF1, bF1, acc11, 0, 0, 0);
        }
        __builtin_amdgcn_s_setprio(0);

        const int trow = b0 + tn * 32 + lhi * 4;
        float* op0 = out + ((size_t)trow * Asz + a) * Osz + w * 32 + llo;
        float* op1 = op0 + (size_t)16 * Asz * Osz;
#pragma unroll
        for (int r2 = 0; r2 < 4; ++r2) {
            op0[(size_t)r2 * Asz * Osz]      = acc00[r2];
            op0[(size_t)r2 * Asz * Osz + 16] = acc01[r2];
            op1[(size_t)r2 * Asz * Osz]      = acc10[r2];
            op1[(size_t)r2 * Asz * Osz + 16] = acc11[r2];
        }
    };

#pragma unroll
    for (int i = 0; i < NI / 2; ++i) {
        // ---- tn = 2i (buffer 0): LB holds F(2i+1) ----
        if (2 * i + 2 < NI) FISSUE(LA, 2 * i + 2);   // 2 phases of cover
        COMPUTE_STORE(&sA[0][0], 2 * i);
        FWRITE(LB, 1);                                // sA[1] = F(2i+1)
        asm volatile("s_waitcnt lgkmcnt(0)" ::: "memory");
        __builtin_amdgcn_s_barrier();

        // ---- tn = 2i+1 (buffer 1): LA holds F(2i+2) ----
        if (2 * i + 3 < NI) FISSUE(LB, 2 * i + 3);
        COMPUTE_STORE(&sA[1][0], 2 * i + 1);
        if (2 * i + 2 < NI) {
            FWRITE(LA, 0);                            // sA[0] = F(2i+2)
            asm volatile("s_waitcnt lgkmcnt(0)" ::: "memory");
            __builtin_amdgcn_s_barrier();
        }
    }
#undef FISSUE
#undef FWRITE
}

extern "C" void kernel_launch(void* const* d_in, const int* in_sizes, int n_in,
                              void* d_out, int out_size, void* d_ws, size_t ws_size,
                              hipStream_t stream) {
    const float* x    = (const float*)d_in[0];
    const float* w    = (const float*)d_in[1];
    const float* bias = (const float*)d_in[2];
    float* out        = (float*)d_out;
    al_gemm<<<dim3(256), dim3(512), 0, stream>>>(x, w, bias, out);
}